// Round 6
// baseline (259.229 us; speedup 1.0000x reference)
//
#include <hip/hip_runtime.h>

#define IMG_H 512
#define IMG_W 512
#define RPB 16            // rows per block
#define NLEV 256
#define NB 32             // batch
#define NC 3              // channels
#define NHIST (NB * NC * NLEV)   // 24576 floats

__device__ float g_hist[NHIST];

// fmodf(v+1, 2) - 1, branch-free, exact (a*0.5 exact, trunc exact,
// a-2t is a multiple of ulp(a) with smaller magnitude).
__device__ __forceinline__ float wrap1(float v) {
    float a = v + 1.0f;
    return a - 2.0f * truncf(0.5f * a) - 1.0f;
}

// Residual -> 2 histogram adds. JAX semantics: negative indices wrap (+256)
// BEFORE the bounds check; only then OOB dropped (mode='drop').
__device__ __forceinline__ void accum(float y, float n, float w, float nw,
                                      float* __restrict__ h) {
    float lo = fminf(n, w), hi = fmaxf(n, w);
    float pred = fminf(fmaxf(n + w - nw, lo), hi);
    float res = y - pred;
    float xs = (res + 1.0f) * 127.5f;
    float f = floorf(xs);
    float frac = xs - f;
    int i0 = (int)f;
    int j0 = (i0 < 0) ? i0 + NLEV : i0;
    if ((unsigned)j0 < (unsigned)NLEV) unsafeAtomicAdd(&h[j0], 1.0f - frac);
    int i1 = i0 + 1;
    int j1 = (i1 < 0) ? i1 + NLEV : i1;
    if ((unsigned)j1 < (unsigned)NLEV) unsafeAtomicAdd(&h[j1], frac);
}

__global__ void zero_hist() {
    int i = blockIdx.x * 256 + threadIdx.x;
    if (i < NHIST) g_hist[i] = 0.0f;
}

__global__ __launch_bounds__(512) void hist_kernel(const float* __restrict__ x,
                                                   const float* __restrict__ params) {
    __shared__ float lh[8][NC][NLEV];    // per-wave sub-histograms, 24 KiB
    __shared__ float bnd[8][17][NC];     // lane-63 y boundary per wave, 1.6 KiB
    const int tid = threadIdx.x;
    const int b = blockIdx.x;
    const int r0 = blockIdx.y * RPB;
    const int wv = tid >> 6;
    const int lane = tid & 63;
    const int col = tid;                 // one column per thread

    float* lp = &lh[0][0][0];
    for (int i = tid; i < 8 * NC * NLEV; i += 512) lp[i] = 0.0f;

    float p[12];
#pragma unroll
    for (int i = 0; i < 12; ++i) p[i] = params[i];  // uniform -> SGPRs

    const int hw = IMG_H * IMG_W;
    const float* base = x + (b * 3) * hw + col;

    // ---- Phase A: 51 independent loads into registers (max MLP) ----
    float xr[17], xg[17], xb[17];
#pragma unroll
    for (int rr = 0; rr < 17; ++rr) {
        if (rr > 0 || r0 > 0) {          // rr==0 && r0==0 -> zero pad (block-uniform)
            const float* q = base + (r0 - 1 + rr) * IMG_W;
            xr[rr] = q[0];
            xg[rr] = q[hw];
            xb[rr] = q[2 * hw];
        } else {
            xr[rr] = 0.0f; xg[rr] = 0.0f; xb[rr] = 0.0f;
        }
    }

    // ---- Phase B: transform all rows in registers (transform(0)==0) ----
#pragma unroll
    for (int rr = 0; rr < 17; ++rr) {
        float r0v = xr[rr], g0v = xg[rr], b0v = xb[rr];
        float r1 = r0v + (p[0] * g0v + p[1] * b0v);
        float g1 = g0v + (p[2] * r1 + p[3] * b0v);
        float b1 = b0v + (p[4] * r1 + p[5] * g1);
        float r2 = r1 + (p[6] * g1 + p[7] * b1);
        float g2 = g1 + (p[8] * r2 + p[9] * b1);
        float b2 = b1 + (p[10] * r2 + p[11] * g2);
        xr[rr] = wrap1(r2); xg[rr] = wrap1(g2); xb[rr] = wrap1(b2);
    }

    // ---- boundary exchange: lane 63's column feeds next wave's lane 0 ----
    if (lane == 63) {
#pragma unroll
        for (int rr = 0; rr < 17; ++rr) {
            bnd[wv][rr][0] = xr[rr];
            bnd[wv][rr][1] = xg[rr];
            bnd[wv][rr][2] = xb[rr];
        }
    }
    __syncthreads();   // also covers lh zero-init

    float* h0 = &lh[wv][0][0];
    float* h1 = &lh[wv][1][0];
    float* h2 = &lh[wv][2][0];
    const bool l0 = (lane == 0);
    const int pw = (wv > 0) ? wv - 1 : 0;   // safe index; wv==0 uses 0.f anyway

    // north (own col, prev row) and northwest carried across rows
    float nr = xr[0], ng = xg[0], nb = xb[0];
    float nwr = __shfl_up(nr, 1), nwg = __shfl_up(ng, 1), nwb = __shfl_up(nb, 1);
    {
        float fr = (wv > 0) ? bnd[pw][0][0] : 0.0f;
        float fg = (wv > 0) ? bnd[pw][0][1] : 0.0f;
        float fb = (wv > 0) ? bnd[pw][0][2] : 0.0f;
        if (l0) { nwr = fr; nwg = fg; nwb = fb; }
    }

#pragma unroll
    for (int rr = 1; rr < 17; ++rr) {
        float cr = xr[rr], cg = xg[rr], cb = xb[rr];
        float wr = __shfl_up(cr, 1), wg = __shfl_up(cg, 1), wb = __shfl_up(cb, 1);
        // lane-0 west comes from previous wave's boundary column (LDS broadcast)
        float fr = (wv > 0) ? bnd[pw][rr][0] : 0.0f;
        float fg = (wv > 0) ? bnd[pw][rr][1] : 0.0f;
        float fb = (wv > 0) ? bnd[pw][rr][2] : 0.0f;
        if (l0) { wr = fr; wg = fg; wb = fb; }
        accum(cr, nr, wr, nwr, h0);
        accum(cg, ng, wg, nwg, h1);
        accum(cb, nb, wb, nwb, h2);
        nr = cr; ng = cg; nb = cb;
        nwr = wr; nwg = wg; nwb = wb;
    }
    __syncthreads();

    // flush: sum the 8 sub-histograms, one native global atomic per bin
    for (int i = tid; i < NC * NLEV; i += 512) {
        int c = i >> 8;
        int bin = i & 255;
        float s = 0.0f;
#pragma unroll
        for (int w2 = 0; w2 < 8; ++w2) s += lh[w2][c][bin];
        unsafeAtomicAdd(&g_hist[(b * NC + c) * NLEV + bin], s);
    }
}

__global__ __launch_bounds__(1024) void entropy_kernel(float* __restrict__ out) {
    const float inv_hw = 1.0f / (float)(IMG_H * IMG_W);
    float acc = 0.0f;
    for (int i = threadIdx.x; i < NHIST; i += 1024) {
        float pr = g_hist[i] * inv_hw;
        if (pr > 0.0f) acc -= pr * log2f(pr);
    }
#pragma unroll
    for (int o = 32; o > 0; o >>= 1) acc += __shfl_down(acc, o);
    __shared__ float red[16];
    int wv = threadIdx.x >> 6;
    int lane = threadIdx.x & 63;
    if (lane == 0) red[wv] = acc;
    __syncthreads();
    if (threadIdx.x == 0) {
        float t = 0.0f;
#pragma unroll
        for (int i = 0; i < 16; ++i) t += red[i];
        out[0] = t * (1.0f / (float)(NB * NC) / 8.0f);
    }
}

extern "C" void kernel_launch(void* const* d_in, const int* in_sizes, int n_in,
                              void* d_out, int out_size, void* d_ws, size_t ws_size,
                              hipStream_t stream) {
    const float* x = (const float*)d_in[0];
    const float* params = (const float*)d_in[1];
    float* out = (float*)d_out;

    zero_hist<<<(NHIST + 255) / 256, 256, 0, stream>>>();
    dim3 grid(NB, IMG_H / RPB);   // 32 x 32
    hist_kernel<<<grid, 512, 0, stream>>>(x, params);
    entropy_kernel<<<1, 1024, 0, stream>>>(out);
}

// Round 7
// 250.566 us; speedup vs baseline: 1.0346x; 1.0346x over previous
//
#include <hip/hip_runtime.h>

#define IMG_H 512
#define IMG_W 512
#define RPB 16            // rows per block
#define NLEV 256
#define NB 32             // batch
#define NC 3              // channels
#define NYB (IMG_H / RPB) // 32 y-blocks
#define BINS (NC * NLEV)  // 768 bins per block

// Per-block partial histograms: 1024 blocks x 768 bins = 3 MB. Plain stores,
// no atomics (each slice has exactly one writer). No zeroing needed.
__device__ float g_part[NB * NYB * BINS];
__device__ float g_ent[NB * NC];   // per-(b,c) entropy

// fmodf(v+1, 2) - 1, branch-free, exact.
__device__ __forceinline__ float wrap1(float v) {
    float a = v + 1.0f;
    return a - 2.0f * truncf(0.5f * a) - 1.0f;
}

// Residual -> 2 histogram adds. JAX: negative indices wrap (+256) BEFORE the
// bounds check; only then OOB dropped (mode='drop').
__device__ __forceinline__ void accum(float y, float n, float w, float nw,
                                      float* __restrict__ h) {
    float lo = fminf(n, w), hi = fmaxf(n, w);
    float pred = fminf(fmaxf(n + w - nw, lo), hi);
    float res = y - pred;
    float xs = (res + 1.0f) * 127.5f;
    float f = floorf(xs);
    float frac = xs - f;
    int i0 = (int)f;
    int j0 = (i0 < 0) ? i0 + NLEV : i0;
    if ((unsigned)j0 < (unsigned)NLEV) unsafeAtomicAdd(&h[j0], 1.0f - frac);
    int i1 = i0 + 1;
    int j1 = (i1 < 0) ? i1 + NLEV : i1;
    if ((unsigned)j1 < (unsigned)NLEV) unsafeAtomicAdd(&h[j1], frac);
}

__global__ __launch_bounds__(512) void hist_kernel(const float* __restrict__ x,
                                                   const float* __restrict__ params) {
    __shared__ float lh[8][NC][NLEV];    // per-wave sub-histograms, 24 KiB
    __shared__ float bnd[8][17][NC];     // lane-63 y boundary per wave
    const int tid = threadIdx.x;
    const int b = blockIdx.x;
    const int yb = blockIdx.y;
    const int r0 = yb * RPB;
    const int wv = tid >> 6;
    const int lane = tid & 63;
    const int col = tid;

    float* lp = &lh[0][0][0];
    for (int i = tid; i < 8 * BINS; i += 512) lp[i] = 0.0f;

    float p[12];
#pragma unroll
    for (int i = 0; i < 12; ++i) p[i] = params[i];

    const int hw = IMG_H * IMG_W;
    const float* base = x + (b * 3) * hw + col;

    // Phase A: 51 independent loads into registers
    float xr[17], xg[17], xb[17];
#pragma unroll
    for (int rr = 0; rr < 17; ++rr) {
        if (rr > 0 || r0 > 0) {
            const float* q = base + (r0 - 1 + rr) * IMG_W;
            xr[rr] = q[0];
            xg[rr] = q[hw];
            xb[rr] = q[2 * hw];
        } else {
            xr[rr] = 0.0f; xg[rr] = 0.0f; xb[rr] = 0.0f;
        }
    }

    // Phase B: transform all rows in registers (transform(0)==0)
#pragma unroll
    for (int rr = 0; rr < 17; ++rr) {
        float r0v = xr[rr], g0v = xg[rr], b0v = xb[rr];
        float r1 = r0v + (p[0] * g0v + p[1] * b0v);
        float g1 = g0v + (p[2] * r1 + p[3] * b0v);
        float b1 = b0v + (p[4] * r1 + p[5] * g1);
        float r2 = r1 + (p[6] * g1 + p[7] * b1);
        float g2 = g1 + (p[8] * r2 + p[9] * b1);
        float b2 = b1 + (p[10] * r2 + p[11] * g2);
        xr[rr] = wrap1(r2); xg[rr] = wrap1(g2); xb[rr] = wrap1(b2);
    }

    // boundary exchange: lane 63's column feeds next wave's lane 0
    if (lane == 63) {
#pragma unroll
        for (int rr = 0; rr < 17; ++rr) {
            bnd[wv][rr][0] = xr[rr];
            bnd[wv][rr][1] = xg[rr];
            bnd[wv][rr][2] = xb[rr];
        }
    }
    __syncthreads();

    float* h0 = &lh[wv][0][0];
    float* h1 = &lh[wv][1][0];
    float* h2 = &lh[wv][2][0];
    const bool l0 = (lane == 0);
    const int pw = (wv > 0) ? wv - 1 : 0;

    float nr = xr[0], ng = xg[0], nb = xb[0];
    float nwr = __shfl_up(nr, 1), nwg = __shfl_up(ng, 1), nwb = __shfl_up(nb, 1);
    {
        float fr = (wv > 0) ? bnd[pw][0][0] : 0.0f;
        float fg = (wv > 0) ? bnd[pw][0][1] : 0.0f;
        float fb = (wv > 0) ? bnd[pw][0][2] : 0.0f;
        if (l0) { nwr = fr; nwg = fg; nwb = fb; }
    }

#pragma unroll
    for (int rr = 1; rr < 17; ++rr) {
        float cr = xr[rr], cg = xg[rr], cb = xb[rr];
        float wr = __shfl_up(cr, 1), wg = __shfl_up(cg, 1), wb = __shfl_up(cb, 1);
        float fr = (wv > 0) ? bnd[pw][rr][0] : 0.0f;
        float fg = (wv > 0) ? bnd[pw][rr][1] : 0.0f;
        float fb = (wv > 0) ? bnd[pw][rr][2] : 0.0f;
        if (l0) { wr = fr; wg = fg; wb = fb; }
        accum(cr, nr, wr, nwr, h0);
        accum(cg, ng, wg, nwg, h1);
        accum(cb, nb, wb, nwb, h2);
        nr = cr; ng = cg; nb = cb;
        nwr = wr; nwg = wg; nwb = wb;
    }
    __syncthreads();

    // flush: per-block private partials, plain coalesced stores — NO atomics
    float* dst = g_part + (b * NYB + yb) * BINS;
    for (int i = tid; i < BINS; i += 512) {
        int c = i >> 8;
        int bin = i & 255;
        float s = 0.0f;
#pragma unroll
        for (int w2 = 0; w2 < 8; ++w2) s += lh[w2][c][bin];
        dst[i] = s;
    }
}

// Stage 1: one block per (b,c); thread t owns bin t; sum 32 y-partials,
// entropy terms, block-reduce, one plain store.
__global__ __launch_bounds__(256) void ent_stage1(float* __restrict__ gent) {
    const int g = blockIdx.x;          // b*NC + c
    const int b = g / NC, c = g % NC;
    const int t = threadIdx.x;         // bin
    const float* src = g_part + (b * NYB) * BINS + c * NLEV + t;
    float s = 0.0f;
#pragma unroll
    for (int y = 0; y < NYB; ++y) s += src[y * BINS];
    const float inv_hw = 1.0f / (float)(IMG_H * IMG_W);
    float pr = s * inv_hw;
    float term = (pr > 0.0f) ? -pr * __log2f(pr) : 0.0f;
    // exact log2 (not fast-math approx) to stay within threshold
    term = (pr > 0.0f) ? -pr * log2f(pr) : 0.0f;
#pragma unroll
    for (int o = 32; o > 0; o >>= 1) term += __shfl_down(term, o);
    __shared__ float red[4];
    if ((t & 63) == 0) red[t >> 6] = term;
    __syncthreads();
    if (t == 0) gent[g] = red[0] + red[1] + red[2] + red[3];
}

// Stage 2: sum the 96 per-(b,c) entropies -> scalar
__global__ __launch_bounds__(128) void ent_stage2(const float* __restrict__ gent,
                                                  float* __restrict__ out) {
    const int t = threadIdx.x;
    float v = (t < NB * NC) ? gent[t] : 0.0f;
#pragma unroll
    for (int o = 32; o > 0; o >>= 1) v += __shfl_down(v, o);
    __shared__ float red[2];
    if ((t & 63) == 0) red[t >> 6] = v;
    __syncthreads();
    if (t == 0) out[0] = (red[0] + red[1]) * (1.0f / (float)(NB * NC) / 8.0f);
}

extern "C" void kernel_launch(void* const* d_in, const int* in_sizes, int n_in,
                              void* d_out, int out_size, void* d_ws, size_t ws_size,
                              hipStream_t stream) {
    const float* x = (const float*)d_in[0];
    const float* params = (const float*)d_in[1];
    float* out = (float*)d_out;

    float* gent;
    hipGetSymbolAddress((void**)&gent, HIP_SYMBOL(g_ent));

    dim3 grid(NB, NYB);   // 32 x 32
    hist_kernel<<<grid, 512, 0, stream>>>(x, params);
    ent_stage1<<<NB * NC, 256, 0, stream>>>(gent);
    ent_stage2<<<1, 128, 0, stream>>>(gent, out);
}

// Round 8
// 51.959 us; speedup vs baseline: 4.9891x; 4.8224x over previous
//
#include <hip/hip_runtime.h>

#define IMG_H 512
#define IMG_W 512
#define RPB 16            // rows per block
#define NLEV 256
#define NB 32             // batch
#define NC 3              // channels
#define NYB (IMG_H / RPB) // 32 y-blocks
#define BINS (NC * NLEV)  // 768 bins per block
#define NBLK (NB * NYB)   // 1024 blocks

// Per-block partials (plain stores, single writer, no zeroing needed):
__device__ unsigned g_cnt[NBLK * BINS];    // 3 MB: per-bin counts
__device__ unsigned g_fq [NBLK * BINS];    // 3 MB: per-bin frac sums (x1024)
__device__ unsigned g_dropQ[NBLK * NC];    // rare: frac dropped at i0==255
__device__ float    g_ent[NB * NC];        // per-(b,c) entropy

// fmodf(v+1, 2) - 1, branch-free, exact.
__device__ __forceinline__ float wrap1(float v) {
    float a = v + 1.0f;
    return a - 2.0f * truncf(0.5f * a) - 1.0f;
}

// Residual -> ONE packed u32 LDS atomic: {count:11 | fracQ:21}, frac
// quantized to 1/1024 (round-nearest). JAX negative-index wrap (+256)
// before bounds check; i0==255's frac is dropped (tracked separately).
__device__ __forceinline__ void accum(float y, float n, float w, float nw,
                                      unsigned* __restrict__ h,
                                      unsigned* __restrict__ drop) {
    float lo = fminf(n, w), hi = fmaxf(n, w);
    float pred = fminf(fmaxf(n + w - nw, lo), hi);
    float xs = (y - pred + 1.0f) * 127.5f;
    float f = floorf(xs);
    float frac = xs - f;
    int i0 = (int)f;
    unsigned fq = (unsigned)(frac * 1024.0f + 0.5f);   // 0..1024
    int j0 = (i0 < 0) ? i0 + NLEV : i0;                // wrap negatives
    if ((unsigned)j0 < (unsigned)NLEV) {
        atomicAdd(&h[j0], (1u << 21) | fq);            // native ds_add_u32
        if (i0 == NLEV - 1) atomicAdd(drop, fq);       // rare: frac is OOB
    }
    // i0 in [256,382]: both contributions dropped -> nothing.
}

__global__ __launch_bounds__(512) void hist_kernel(const float* __restrict__ x,
                                                   const float* __restrict__ params) {
    __shared__ unsigned lhw[8][NC][NLEV];   // per-wave packed histograms, 24 KiB
    __shared__ float bnd[8][17][NC];        // lane-63 y boundary per wave
    __shared__ unsigned dropw[NC];
    const int tid = threadIdx.x;
    const int b = blockIdx.x;
    const int yb = blockIdx.y;
    const int r0 = yb * RPB;
    const int wv = tid >> 6;
    const int lane = tid & 63;
    const int col = tid;

    unsigned* lp = &lhw[0][0][0];
    for (int i = tid; i < 8 * BINS; i += 512) lp[i] = 0u;
    if (tid < NC) dropw[tid] = 0u;

    float p[12];
#pragma unroll
    for (int i = 0; i < 12; ++i) p[i] = params[i];

    const int hw = IMG_H * IMG_W;
    const float* base = x + (b * 3) * hw + col;

    // Phase A: 51 independent loads into registers (max MLP)
    float xr[17], xg[17], xb[17];
#pragma unroll
    for (int rr = 0; rr < 17; ++rr) {
        if (rr > 0 || r0 > 0) {
            const float* q = base + (r0 - 1 + rr) * IMG_W;
            xr[rr] = q[0];
            xg[rr] = q[hw];
            xb[rr] = q[2 * hw];
        } else {
            xr[rr] = 0.0f; xg[rr] = 0.0f; xb[rr] = 0.0f;
        }
    }

    // Phase B: transform all rows in registers (transform(0)==0)
#pragma unroll
    for (int rr = 0; rr < 17; ++rr) {
        float r0v = xr[rr], g0v = xg[rr], b0v = xb[rr];
        float r1 = r0v + (p[0] * g0v + p[1] * b0v);
        float g1 = g0v + (p[2] * r1 + p[3] * b0v);
        float b1 = b0v + (p[4] * r1 + p[5] * g1);
        float r2 = r1 + (p[6] * g1 + p[7] * b1);
        float g2 = g1 + (p[8] * r2 + p[9] * b1);
        float b2 = b1 + (p[10] * r2 + p[11] * g2);
        xr[rr] = wrap1(r2); xg[rr] = wrap1(g2); xb[rr] = wrap1(b2);
    }

    // boundary exchange: lane 63's column feeds next wave's lane 0
    if (lane == 63) {
#pragma unroll
        for (int rr = 0; rr < 17; ++rr) {
            bnd[wv][rr][0] = xr[rr];
            bnd[wv][rr][1] = xg[rr];
            bnd[wv][rr][2] = xb[rr];
        }
    }
    __syncthreads();

    unsigned* h0 = &lhw[wv][0][0];
    unsigned* h1 = &lhw[wv][1][0];
    unsigned* h2 = &lhw[wv][2][0];
    const bool l0 = (lane == 0);
    const int pw = (wv > 0) ? wv - 1 : 0;

    float nr = xr[0], ng = xg[0], nb = xb[0];
    float nwr = __shfl_up(nr, 1), nwg = __shfl_up(ng, 1), nwb = __shfl_up(nb, 1);
    {
        float fr = (wv > 0) ? bnd[pw][0][0] : 0.0f;
        float fg = (wv > 0) ? bnd[pw][0][1] : 0.0f;
        float fb = (wv > 0) ? bnd[pw][0][2] : 0.0f;
        if (l0) { nwr = fr; nwg = fg; nwb = fb; }
    }

#pragma unroll
    for (int rr = 1; rr < 17; ++rr) {
        float cr = xr[rr], cg = xg[rr], cb = xb[rr];
        float wr = __shfl_up(cr, 1), wg = __shfl_up(cg, 1), wb = __shfl_up(cb, 1);
        float fr = (wv > 0) ? bnd[pw][rr][0] : 0.0f;
        float fg = (wv > 0) ? bnd[pw][rr][1] : 0.0f;
        float fb = (wv > 0) ? bnd[pw][rr][2] : 0.0f;
        if (l0) { wr = fr; wg = fg; wb = fb; }
        accum(cr, nr, wr, nwr, h0, &dropw[0]);
        accum(cg, ng, wg, nwg, h1, &dropw[1]);
        accum(cb, nb, wb, nwb, h2, &dropw[2]);
        nr = cr; ng = cg; nb = cb;
        nwr = wr; nwg = wg; nwb = wb;
    }
    __syncthreads();

    // flush: unpack + sum 8 waves, plain coalesced stores — NO atomics
    const int blk = b * NYB + yb;
    unsigned* dc = g_cnt + blk * BINS;
    unsigned* df = g_fq + blk * BINS;
    for (int i = tid; i < BINS; i += 512) {
        int c = i >> 8;
        int bin = i & 255;
        unsigned cs = 0, qs = 0;
#pragma unroll
        for (int w2 = 0; w2 < 8; ++w2) {
            unsigned v = lhw[w2][c][bin];
            cs += v >> 21;
            qs += v & 0x1FFFFFu;
        }
        dc[i] = cs;
        df[i] = qs;
    }
    if (tid < NC) g_dropQ[blk * NC + tid] = dropw[tid];
}

// Stage 1: one block per (b,c); thread t owns bin t. Sum 32 y-partials,
// reconstruct hist[t] = cnt - fq/1024 + pass/1024, entropy term, reduce.
__global__ __launch_bounds__(256) void ent_stage1() {
    const int g = blockIdx.x;          // b*NC + c
    const int b = g / NC, c = g % NC;
    const int t = threadIdx.x;         // bin
    const unsigned* sc = g_cnt + b * NYB * BINS + c * NLEV + t;
    const unsigned* sf = g_fq  + b * NYB * BINS + c * NLEV + t;
    unsigned cnt = 0, fq = 0;
#pragma unroll
    for (int y = 0; y < NYB; ++y) {
        cnt += sc[y * BINS];
        fq  += sf[y * BINS];
    }
    __shared__ unsigned fsb[NLEV];
    __shared__ unsigned dsh;
    fsb[t] = fq;
    if (t == 0) {
        unsigned d = 0;
        for (int y = 0; y < NYB; ++y) d += g_dropQ[(b * NYB + y) * NC + c];
        dsh = d;
    }
    __syncthreads();
    // pass-in from previous bin; bin 0 receives bin 255's frac minus dropped
    unsigned passq = (t == 0) ? (fsb[NLEV - 1] - dsh) : fsb[t - 1];
    float hist = (float)cnt + ((float)passq - (float)fq) * (1.0f / 1024.0f);
    float pr = hist * (1.0f / (float)(IMG_H * IMG_W));
    float term = (pr > 0.0f) ? -pr * log2f(pr) : 0.0f;
#pragma unroll
    for (int o = 32; o > 0; o >>= 1) term += __shfl_down(term, o);
    __shared__ float red[4];
    if ((t & 63) == 0) red[t >> 6] = term;
    __syncthreads();
    if (t == 0) g_ent[g] = red[0] + red[1] + red[2] + red[3];
}

// Stage 2: sum the 96 per-(b,c) entropies -> scalar
__global__ __launch_bounds__(128) void ent_stage2(float* __restrict__ out) {
    const int t = threadIdx.x;
    float v = (t < NB * NC) ? g_ent[t] : 0.0f;
#pragma unroll
    for (int o = 32; o > 0; o >>= 1) v += __shfl_down(v, o);
    __shared__ float red[2];
    if ((t & 63) == 0) red[t >> 6] = v;
    __syncthreads();
    if (t == 0) out[0] = (red[0] + red[1]) * (1.0f / (float)(NB * NC) / 8.0f);
}

extern "C" void kernel_launch(void* const* d_in, const int* in_sizes, int n_in,
                              void* d_out, int out_size, void* d_ws, size_t ws_size,
                              hipStream_t stream) {
    const float* x = (const float*)d_in[0];
    const float* params = (const float*)d_in[1];
    float* out = (float*)d_out;

    dim3 grid(NB, NYB);   // 32 x 32
    hist_kernel<<<grid, 512, 0, stream>>>(x, params);
    ent_stage1<<<NB * NC, 256, 0, stream>>>();
    ent_stage2<<<1, 128, 0, stream>>>(out);
}

// Round 9
// 50.335 us; speedup vs baseline: 5.1501x; 1.0323x over previous
//
#include <hip/hip_runtime.h>

#define IMG_H 512
#define IMG_W 512
#define RPB 8             // rows per block
#define NROW (RPB + 1)    // 9 (incl. north halo)
#define NLEV 256
#define NB 32
#define NC 3
#define NYB (IMG_H / RPB) // 64
#define BINS (NC * NLEV)  // 768
#define NBLK (NB * NYB)   // 2048
#define NTHR 256
#define NWAVE (NTHR / 64) // 4

// Per-block partials (plain stores, single writer, no zeroing needed):
__device__ unsigned g_cnt[NBLK * BINS];    // 6.3 MB
__device__ unsigned g_fq [NBLK * BINS];    // 6.3 MB
__device__ unsigned g_dropQ[NBLK * NC];
__device__ float    g_ent[NB * NC];

// fmodf(v+1,2)-1, branch-free, exact.
__device__ __forceinline__ float wrap1(float v) {
    float a = v + 1.0f;
    return a - 2.0f * truncf(0.5f * a) - 1.0f;
}

__device__ __forceinline__ void xform(float& r, float& g, float& bl,
                                      const float* __restrict__ p) {
    float r1 = r + (p[0] * g + p[1] * bl);
    float g1 = g + (p[2] * r1 + p[3] * bl);
    float b1 = bl + (p[4] * r1 + p[5] * g1);
    float r2 = r1 + (p[6] * g1 + p[7] * b1);
    float g2 = g1 + (p[8] * r2 + p[9] * b1);
    float b2 = b1 + (p[10] * r2 + p[11] * g2);
    r = wrap1(r2); g = wrap1(g2); bl = wrap1(b2);
}

// Residual -> ONE packed u32 LDS atomic: {count:11 | fracQ:21}. JAX
// negative-index wrap (+256) before bounds check; i0==255 frac dropped
// (tracked). Max 1024 contribs/bin/wave-channel -> no overflow.
__device__ __forceinline__ void accum(float y, float n, float w, float nw,
                                      unsigned* __restrict__ h,
                                      unsigned* __restrict__ drop) {
    float lo = fminf(n, w), hi = fmaxf(n, w);
    float pred = fminf(fmaxf(n + w - nw, lo), hi);
    float xs = (y - pred + 1.0f) * 127.5f;
    float f = floorf(xs);
    float frac = xs - f;
    int i0 = (int)f;
    unsigned fq = (unsigned)(frac * 1024.0f + 0.5f);
    int j0 = (i0 < 0) ? i0 + NLEV : i0;
    if ((unsigned)j0 < (unsigned)NLEV) {
        atomicAdd(&h[j0], (1u << 21) | fq);
        if (i0 == NLEV - 1) atomicAdd(drop, fq);
    }
}

__global__ __launch_bounds__(NTHR) void hist_kernel(const float* __restrict__ x,
                                                    const float* __restrict__ params) {
    __shared__ unsigned lhw[NWAVE][NC][NLEV];  // 12 KiB packed hists
    __shared__ float bnd[NWAVE][NROW][NC];     // lane-63 odd-col y per wave
    __shared__ unsigned dropw[NC];
    const int tid = threadIdx.x;
    const int b = blockIdx.x;
    const int yb = blockIdx.y;
    const int r0 = yb * RPB;
    const int wv = tid >> 6;
    const int lane = tid & 63;

    unsigned* lp = &lhw[0][0][0];
#pragma unroll
    for (int i = tid; i < NWAVE * BINS; i += NTHR) lp[i] = 0u;
    if (tid < NC) dropw[tid] = 0u;

    float p[12];
#pragma unroll
    for (int i = 0; i < 12; ++i) p[i] = params[i];

    const int hw = IMG_H * IMG_W;
    // thread owns cols {2*tid, 2*tid+1}; float2 units
    const float2* base = (const float2*)(x + (size_t)(b * 3) * hw) + tid;

    // Phase A: 27 independent float2 loads
    float a0[NROW], a1[NROW], c0[NROW], c1[NROW], e0[NROW], e1[NROW];
#pragma unroll
    for (int rr = 0; rr < NROW; ++rr) {
        if (rr > 0 || r0 > 0) {
            int ro = (r0 - 1 + rr) * (IMG_W / 2);
            float2 vr = base[ro];
            float2 vg = base[ro + hw / 2];
            float2 vb = base[ro + hw];
            a0[rr] = vr.x; a1[rr] = vr.y;
            c0[rr] = vg.x; c1[rr] = vg.y;
            e0[rr] = vb.x; e1[rr] = vb.y;
        } else {
            a0[rr] = a1[rr] = c0[rr] = c1[rr] = e0[rr] = e1[rr] = 0.0f;
        }
    }

    // Phase B: transform both columns, all rows (transform(0)==0)
#pragma unroll
    for (int rr = 0; rr < NROW; ++rr) {
        xform(a0[rr], c0[rr], e0[rr], p);
        xform(a1[rr], c1[rr], e1[rr], p);
    }

    // boundary: lane 63's odd col feeds next wave's lane 0
    if (lane == 63) {
#pragma unroll
        for (int rr = 0; rr < NROW; ++rr) {
            bnd[wv][rr][0] = a1[rr];
            bnd[wv][rr][1] = c1[rr];
            bnd[wv][rr][2] = e1[rr];
        }
    }
    __syncthreads();

    // stage prev wave's 27 boundary words with ONE ds_read; extract later
    // via v_readlane (compile-time lane index) -> zero DS ops in the loop.
    const int pw = (wv > 0) ? wv - 1 : 0;
    const float* pwb = &bnd[pw][0][0];
    float bv = pwb[lane < NROW * NC ? lane : 0];
    const bool lz = (lane == 0);

#define RDL(rr, ch) __int_as_float(__builtin_amdgcn_readlane(__float_as_int(bv), (rr) * NC + (ch)))

    unsigned* h0 = &lhw[wv][0][0];
    unsigned* h1 = &lhw[wv][1][0];
    unsigned* h2 = &lhw[wv][2][0];

    // carries: north (both cols) + northwest (even col only; nw of odd = n of even)
    float nA0 = a0[0], nA1 = a1[0];
    float nC0 = c0[0], nC1 = c1[0];
    float nE0 = e0[0], nE1 = e1[0];
    float nwA = __shfl_up(a1[0], 1);
    float nwC = __shfl_up(c1[0], 1);
    float nwE = __shfl_up(e1[0], 1);
    {
        float bA = (wv > 0) ? RDL(0, 0) : 0.0f;
        float bC = (wv > 0) ? RDL(0, 1) : 0.0f;
        float bE = (wv > 0) ? RDL(0, 2) : 0.0f;
        if (lz) { nwA = bA; nwC = bC; nwE = bE; }
    }

#pragma unroll
    for (int rr = 1; rr < NROW; ++rr) {
        float uA0 = a0[rr], uA1 = a1[rr];
        float uC0 = c0[rr], uC1 = c1[rr];
        float uE0 = e0[rr], uE1 = e1[rr];
        float vA = __shfl_up(uA1, 1);
        float vC = __shfl_up(uC1, 1);
        float vE = __shfl_up(uE1, 1);
        float bA = (wv > 0) ? RDL(rr, 0) : 0.0f;
        float bC = (wv > 0) ? RDL(rr, 1) : 0.0f;
        float bE = (wv > 0) ? RDL(rr, 2) : 0.0f;
        if (lz) { vA = bA; vC = bC; vE = bE; }
        // even col: west = vX, nw = nwX ; odd col: west = even cur, nw = even north
        accum(uA0, nA0, vA, nwA, h0, &dropw[0]);
        accum(uA1, nA1, uA0, nA0, h0, &dropw[0]);
        accum(uC0, nC0, vC, nwC, h1, &dropw[1]);
        accum(uC1, nC1, uC0, nC0, h1, &dropw[1]);
        accum(uE0, nE0, vE, nwE, h2, &dropw[2]);
        accum(uE1, nE1, uE0, nE0, h2, &dropw[2]);
        nwA = vA; nA0 = uA0; nA1 = uA1;
        nwC = vC; nC0 = uC0; nC1 = uC1;
        nwE = vE; nE0 = uE0; nE1 = uE1;
    }
    __syncthreads();

    // flush: unpack + sum 4 waves, plain coalesced stores
    const int blk = b * NYB + yb;
    unsigned* dc = g_cnt + (size_t)blk * BINS;
    unsigned* df = g_fq + (size_t)blk * BINS;
#pragma unroll
    for (int i = tid; i < BINS; i += NTHR) {
        int c = i >> 8, bin = i & 255;
        unsigned cs = 0, qs = 0;
#pragma unroll
        for (int w2 = 0; w2 < NWAVE; ++w2) {
            unsigned v = lhw[w2][c][bin];
            cs += v >> 21;
            qs += v & 0x1FFFFFu;
        }
        dc[i] = cs; df[i] = qs;
    }
    if (tid < NC) g_dropQ[blk * NC + tid] = dropw[tid];
}

// Stage 1: one block per (b,c); thread t owns bin t. Sum 64 y-partials,
// reconstruct hist = cnt - fq/1024 + pass/1024, entropy term, reduce.
__global__ __launch_bounds__(256) void ent_stage1() {
    const int g = blockIdx.x;
    const int b = g / NC, c = g % NC;
    const int t = threadIdx.x;
    const unsigned* sc = g_cnt + (size_t)b * NYB * BINS + c * NLEV + t;
    const unsigned* sf = g_fq  + (size_t)b * NYB * BINS + c * NLEV + t;
    unsigned cnt = 0, fq = 0;
#pragma unroll
    for (int y = 0; y < NYB; ++y) {
        cnt += sc[(size_t)y * BINS];
        fq  += sf[(size_t)y * BINS];
    }
    __shared__ unsigned fsb[NLEV];
    __shared__ unsigned dsh;
    fsb[t] = fq;
    if (t < 64) {   // parallel drop-sum over 64 y-blocks
        unsigned d = g_dropQ[(b * NYB + t) * NC + c];
#pragma unroll
        for (int o = 32; o > 0; o >>= 1) d += __shfl_down(d, o);
        if (t == 0) dsh = d;
    }
    __syncthreads();
    // pass-in from previous bin; bin 0 receives bin 255's frac minus dropped
    unsigned passq = (t == 0) ? (fsb[NLEV - 1] - dsh) : fsb[t - 1];
    float hist = (float)cnt + ((float)passq - (float)fq) * (1.0f / 1024.0f);
    float pr = hist * (1.0f / (float)(IMG_H * IMG_W));
    float term = (pr > 0.0f) ? -pr * log2f(pr) : 0.0f;
#pragma unroll
    for (int o = 32; o > 0; o >>= 1) term += __shfl_down(term, o);
    __shared__ float red[4];
    if ((t & 63) == 0) red[t >> 6] = term;
    __syncthreads();
    if (t == 0) g_ent[g] = red[0] + red[1] + red[2] + red[3];
}

__global__ __launch_bounds__(128) void ent_stage2(float* __restrict__ out) {
    const int t = threadIdx.x;
    float v = (t < NB * NC) ? g_ent[t] : 0.0f;
#pragma unroll
    for (int o = 32; o > 0; o >>= 1) v += __shfl_down(v, o);
    __shared__ float red[2];
    if ((t & 63) == 0) red[t >> 6] = v;
    __syncthreads();
    if (t == 0) out[0] = (red[0] + red[1]) * (1.0f / (float)(NB * NC) / 8.0f);
}

extern "C" void kernel_launch(void* const* d_in, const int* in_sizes, int n_in,
                              void* d_out, int out_size, void* d_ws, size_t ws_size,
                              hipStream_t stream) {
    const float* x = (const float*)d_in[0];
    const float* params = (const float*)d_in[1];
    float* out = (float*)d_out;

    dim3 grid(NB, NYB);   // 32 x 64
    hist_kernel<<<grid, NTHR, 0, stream>>>(x, params);
    ent_stage1<<<NB * NC, 256, 0, stream>>>();
    ent_stage2<<<1, 128, 0, stream>>>(out);
}